// Round 7
// baseline (794.080 us; speedup 1.0000x reference)
//
#include <hip/hip_runtime.h>
#include <math.h>

typedef unsigned long long U64;
typedef _Float16 half8 __attribute__((ext_vector_type(8)));
typedef float f32x16 __attribute__((ext_vector_type(16)));

__device__ const float g_bw[9] = {91.f, 181.f, 362.f, 64.f, 128.f, 256.f, 45.f, 91.f, 181.f};
__device__ const float g_bh[9] = {45.f, 91.f, 181.f, 64.f, 128.f, 256.f, 91.f, 181.f, 362.f};

__device__ inline f32x16 zero16() {
    f32x16 z;
#pragma unroll
    for (int i = 0; i < 16; ++i) z[i] = 0.f;
    return z;
}

#define GLOAD16(G, L)                                                  \
    __builtin_amdgcn_global_load_lds(                                  \
        (const __attribute__((address_space(1))) void*)(G),            \
        (__attribute__((address_space(3))) void*)(L), 16, 0, 0)

// ---------------------------------------------------------------------------
// K_prep (FUSED): bid<512 fm interior transpose; 512..771 halo zero; >=772 w.
// fpi[b][hp][wp][chunk 0..15][64], chunk inner = [hi x32 | lo x32]
// wki[o][chunk=tap*16+cg][64], same inner layout.
// ---------------------------------------------------------------------------
__global__ __launch_bounds__(256) void k_prep(const float* __restrict__ fm,
                                              const float* __restrict__ w_conv,
                                              _Float16* __restrict__ fpi,
                                              _Float16* __restrict__ wki) {
    __shared__ float smem[4608];  // union: fm tile (64x65<4608? no: 4160) / w row
    int bid = blockIdx.x, b = blockIdx.y;
    int t = threadIdx.x;
    if (bid >= 772) {  // weights: o = (bid-772) + b*128
        int o = (bid - 772) + b * 128;
        for (int e = t; e < 4608; e += 256) smem[e] = w_conv[(size_t)o * 4608 + e];
        __syncthreads();
        for (int e = t; e < 9216; e += 256) {
            int s = e & 63, chunk = e >> 6;
            int tap = chunk >> 4, cgi = chunk & 15;
            int c = cgi * 32 + (s & 31);
            float x = smem[c * 9 + tap];
            _Float16 hi = (_Float16)x;
            wki[(size_t)o * 9216 + e] = (s < 32) ? hi : (_Float16)((x - (float)hi) * 2048.0f);
        }
        return;
    }
    if (bid >= 512) {  // halo: 260 cells per batch
        int ci = bid - 512;
        int hp, wp;
        if (ci < 66)       { hp = 0;  wp = ci; }
        else if (ci < 132) { hp = 65; wp = ci - 66; }
        else { int k = ci - 132; hp = 1 + (k & 63); wp = (k < 64) ? 0 : 65; }
        uint2 z; z.x = 0u; z.y = 0u;
        *(uint2*)(fpi + ((size_t)(b * 66 + hp) * 66 + wp) * 1024 + t * 4) = z;
        return;
    }
    // interior transpose: tile[c][w] with pad
    float (*tile)[65] = (float(*)[65])smem;  // 64x65 = 4160 floats
    int cg = bid & 7, h = bid >> 3;
    int cl = t >> 2, w0 = (t & 3) * 16;
    const float* src = fm + (((size_t)(b * 512 + cg * 64 + cl) * 64 + h) * 64 + w0);
#pragma unroll
    for (int l = 0; l < 4; ++l) {
        float4 v = *(const float4*)(src + l * 4);
        tile[cl][w0 + l * 4 + 0] = v.x; tile[cl][w0 + l * 4 + 1] = v.y;
        tile[cl][w0 + l * 4 + 2] = v.z; tile[cl][w0 + l * 4 + 3] = v.w;
    }
    __syncthreads();
    int w = t & 63, pth = t >> 6;
    int chunkrel = pth >> 1, half = pth & 1;
    _Float16* dst = fpi + ((size_t)((b * 66 + h + 1) * 66) + (w + 1)) * 1024 +
                    (cg * 2 + chunkrel) * 64 + half * 32;
#pragma unroll
    for (int g8 = 0; g8 < 4; ++g8) {
        half8 v;
#pragma unroll
        for (int i = 0; i < 8; ++i) {
            float x = tile[chunkrel * 32 + g8 * 8 + i][w];
            _Float16 hi = (_Float16)x;
            v[i] = half ? (_Float16)((x - (float)hi) * 2048.0f) : hi;
        }
        *(half8*)(dst + g8 * 8) = v;
    }
}

// ---------------------------------------------------------------------------
// K_conv_mfma: implicit-GEMM 3x3 conv, mfma_f32_32x32x16_f16 hi/lo split.
// Round-7 pipeline: fragment ds_reads for tile it+1 issued during tile it's
// second MFMA half (cross-buffer prefetch). Each buffer is fully read by the
// TOP of its iteration -> DMA(it+2) issues right after barrier A, before the
// counted vmcnt(8) -> reads, DMA and MFMA overlap on separate pipes.
// ---------------------------------------------------------------------------
__global__ __launch_bounds__(256, 2) void k_conv_mfma(
    const _Float16* __restrict__ fpi, const _Float16* __restrict__ wki,
    const float* __restrict__ bconv, float* __restrict__ feat) {
    __shared__ _Float16 As[2][128][64];
    __shared__ _Float16 Bs[2][128][64];
    const int t = threadIdx.x;
    const int lane = t & 63, wv = t >> 6;
    const int wm = wv >> 1, wn = wv & 1;
    int flat = (int)blockIdx.x + 128 * (int)blockIdx.y;
    int fid = (flat & 7) * 64 + (flat >> 3);
    const int p0 = (fid >> 2) * 128, o0 = (fid & 3) * 128;

    const char* baseA[4];
    const char* baseB[4];
#pragma unroll
    for (int q = 0; q < 4; ++q) {
        int row = wv * 32 + q * 8 + (lane >> 3);
        int qs = (lane & 7) ^ (row & 7);
        int P = p0 + row;
        int bb = P >> 12, hh = (P >> 6) & 63, ww = P & 63;
        baseA[q] = (const char*)fpi + ((size_t)((bb * 66 + hh) * 66 + ww)) * 2048 + qs * 16;
        baseB[q] = (const char*)wki + (size_t)(o0 + row) * 18432 + qs * 16;
    }

    f32x16 acc0[2][2], acc1[2][2];
#pragma unroll
    for (int mi = 0; mi < 2; ++mi)
#pragma unroll
        for (int ni = 0; ni < 2; ++ni) { acc0[mi][ni] = zero16(); acc1[mi][ni] = zero16(); }

    auto issue = [&](int it2, int buf) {
        int tap = it2 >> 4;
        int ry = (tap * 11) >> 5, rx = tap - ry * 3;
        int ka = (ry * 66 + rx) * 2048 + (it2 & 15) * 128;
        int kb = it2 * 128;
#pragma unroll
        for (int q = 0; q < 4; ++q) {
            GLOAD16(baseA[q] + ka, &As[buf][wv * 32 + q * 8][0]);
            GLOAD16(baseB[q] + kb, &Bs[buf][wv * 32 + q * 8][0]);
        }
    };

    const int lg = (lane >> 5) * 16;
    half8 af[2][2][2], bf[2][2][2];  // [idx][hl][kh]

#define LOADA(mi_, P_)                                                          \
    {                                                                           \
        int rA = wm * 64 + (mi_) * 32 + (lane & 31);                            \
        int xa = (rA & 7) << 4, ba = rA * 128;                                  \
        af[mi_][0][0] = *(const half8*)((P_) + ba + ((0 + lg) ^ xa));           \
        af[mi_][0][1] = *(const half8*)((P_) + ba + ((32 + lg) ^ xa));          \
        af[mi_][1][0] = *(const half8*)((P_) + ba + ((64 + lg) ^ xa));          \
        af[mi_][1][1] = *(const half8*)((P_) + ba + ((96 + lg) ^ xa));          \
    }
#define LOADB(ni_, P_)                                                          \
    {                                                                           \
        int rB = wn * 64 + (ni_) * 32 + (lane & 31);                            \
        int xb = (rB & 7) << 4, bb0 = rB * 128;                                 \
        bf[ni_][0][0] = *(const half8*)((P_) + bb0 + ((0 + lg) ^ xb));          \
        bf[ni_][0][1] = *(const half8*)((P_) + bb0 + ((32 + lg) ^ xb));         \
        bf[ni_][1][0] = *(const half8*)((P_) + bb0 + ((64 + lg) ^ xb));         \
        bf[ni_][1][1] = *(const half8*)((P_) + bb0 + ((96 + lg) ^ xb));         \
    }
#define QUAD(mi_, ni_)                                                                                     \
    acc0[mi_][ni_] = __builtin_amdgcn_mfma_f32_32x32x16_f16(af[mi_][0][0], bf[ni_][0][0], acc0[mi_][ni_], 0, 0, 0); \
    acc0[mi_][ni_] = __builtin_amdgcn_mfma_f32_32x32x16_f16(af[mi_][0][1], bf[ni_][0][1], acc0[mi_][ni_], 0, 0, 0); \
    acc1[mi_][ni_] = __builtin_amdgcn_mfma_f32_32x32x16_f16(af[mi_][0][0], bf[ni_][1][0], acc1[mi_][ni_], 0, 0, 0); \
    acc1[mi_][ni_] = __builtin_amdgcn_mfma_f32_32x32x16_f16(af[mi_][0][1], bf[ni_][1][1], acc1[mi_][ni_], 0, 0, 0); \
    acc1[mi_][ni_] = __builtin_amdgcn_mfma_f32_32x32x16_f16(af[mi_][1][0], bf[ni_][0][0], acc1[mi_][ni_], 0, 0, 0); \
    acc1[mi_][ni_] = __builtin_amdgcn_mfma_f32_32x32x16_f16(af[mi_][1][1], bf[ni_][0][1], acc1[mi_][ni_], 0, 0, 0);

    issue(0, 0);
    issue(1, 1);
    asm volatile("s_waitcnt vmcnt(8)" ::: "memory");
    __builtin_amdgcn_s_barrier();
    __builtin_amdgcn_sched_barrier(0);
    {   // prologue: fragments of tile 0 from buf0
        const char* ab = (const char*)As;
        const char* bb2 = (const char*)Bs;
        LOADA(0, ab) LOADA(1, ab) LOADB(0, bb2) LOADB(1, bb2)
    }

    for (int it = 0; it < 144; ++it) {
        int cur = it & 1;
        // top: all my LDS reads (incl. frags of this tile, read last iter) done
        asm volatile("s_waitcnt lgkmcnt(0)" ::: "memory");
        __builtin_amdgcn_sched_barrier(0);
        __builtin_amdgcn_s_barrier();  // A: buf cur fully read by ALL waves
        __builtin_amdgcn_sched_barrier(0);
        if (it <= 141) issue(it + 2, cur);  // DMA into the now-dead buffer
        __builtin_amdgcn_sched_barrier(0);
        __builtin_amdgcn_s_setprio(1);
        QUAD(0, 0) QUAD(1, 0)               // 12 MFMA (af*, bf0)
        __builtin_amdgcn_s_setprio(0);
        __builtin_amdgcn_sched_barrier(0);
        if (it <= 141)      { asm volatile("s_waitcnt vmcnt(8)" ::: "memory"); }
        else if (it == 142) { asm volatile("s_waitcnt vmcnt(0)" ::: "memory"); }
        __builtin_amdgcn_sched_barrier(0);
        __builtin_amdgcn_s_barrier();  // B: buf nxt (tile it+1) visible
        __builtin_amdgcn_sched_barrier(0);
        if (it <= 142) {
            const char* ab = (const char*)As + (cur ^ 1) * 16384;
            const char* bb2 = (const char*)Bs + (cur ^ 1) * 16384;
            LOADB(0, bb2)                   // bf0 dead after QUAD(1,0)
            __builtin_amdgcn_s_setprio(1);
            QUAD(0, 1)                      // af0, bf1
            __builtin_amdgcn_s_setprio(0);
            LOADA(0, ab)                    // af0 dead
            __builtin_amdgcn_s_setprio(1);
            QUAD(1, 1)                      // af1, bf1
            __builtin_amdgcn_s_setprio(0);
            LOADA(1, ab) LOADB(1, bb2)      // af1, bf1 dead
        } else {
            QUAD(0, 1) QUAD(1, 1)
        }
    }

    // epilogue: combine + bias + relu; C/D map col=lane&31, row=(q&3)+8*(q>>2)+4*(lane>>5)
#pragma unroll
    for (int mi = 0; mi < 2; ++mi)
#pragma unroll
        for (int ni = 0; ni < 2; ++ni) {
            int col = o0 + wn * 64 + ni * 32 + (lane & 31);
            float bv = bconv[col];
            int rbase = p0 + wm * 64 + mi * 32 + 4 * (lane >> 5);
#pragma unroll
            for (int q = 0; q < 16; ++q) {
                int row = rbase + (q & 3) + 8 * (q >> 2);
                float v = acc0[mi][ni][q] + acc1[mi][ni][q] * 4.8828125e-4f + bv;
                feat[(size_t)row * 512 + col] = fmaxf(v, 0.f);
            }
        }
}

// ---------------------------------------------------------------------------
// K_heads: 1x1 heads (4-way channel split + LDS reduce) fused with sigmoid,
// box decode and sort-key build.
// ---------------------------------------------------------------------------
__global__ __launch_bounds__(256) void k_heads(const float* __restrict__ feat,
                                               const float* __restrict__ w_cls,
                                               const float* __restrict__ b_cls,
                                               const float* __restrict__ w_box,
                                               const float* __restrict__ b_box,
                                               U64* __restrict__ keys,
                                               float4* __restrict__ proposals) {
    __shared__ float red[3][64][45];
    int t = threadIdx.x;
    int px = t & 63, cq = t >> 6;
    int p = blockIdx.x * 64 + px;
    const float* fr = feat + (size_t)p * 512 + cq * 128;
    float acc[45];
#pragma unroll
    for (int o = 0; o < 45; ++o) acc[o] = 0.f;
    for (int c = 0; c < 128; c += 4) {
        float4 f = *(const float4*)(fr + c);
#pragma unroll
        for (int o = 0; o < 45; ++o) {
            const float* wr = ((o < 9) ? (w_cls + o * 512) : (w_box + (o - 9) * 512)) + cq * 128 + c;
            acc[o] += f.x * wr[0] + f.y * wr[1] + f.z * wr[2] + f.w * wr[3];
        }
    }
    if (cq > 0) {
#pragma unroll
        for (int o = 0; o < 45; ++o) red[cq - 1][px][o] = acc[o];
    }
    __syncthreads();
    if (cq == 0) {
#pragma unroll
        for (int o = 0; o < 45; ++o) acc[o] += red[0][px][o] + red[1][px][o] + red[2][px][o];
        int b = p >> 12, pixloc = p & 4095;
        int h = pixloc >> 6, w = pixloc & 63;
        int ibase = b * 36864 + pixloc * 9;
#pragma unroll
        for (int a = 0; a < 9; ++a) {
            float logit = acc[a] + b_cls[a];
            float s = 1.f / (1.f + expf(-logit));
            keys[ibase + a] = (((U64)(__float_as_uint(s) ^ 0x80000000u)) << 32) |
                              (unsigned)(~(unsigned)(pixloc * 9 + a));
            float dx = acc[9 + a * 4 + 0] + b_box[a * 4 + 0];
            float dy = acc[9 + a * 4 + 1] + b_box[a * 4 + 1];
            float dw = fminf(acc[9 + a * 4 + 2] + b_box[a * 4 + 2], 4.135166556742356f);
            float dh = fminf(acc[9 + a * 4 + 3] + b_box[a * 4 + 3], 4.135166556742356f);
            float wa = 2.f * g_bw[a], ha = 2.f * g_bh[a];
            float cx = dx * wa + (float)(w * 16);
            float cy = dy * ha + (float)(h * 16);
            float pw = expf(dw) * wa;
            float ph = expf(dh) * ha;
            proposals[ibase + a] =
                make_float4(cx - 0.5f * pw, cy - 0.5f * ph, cx + 0.5f * pw, cy + 0.5f * ph);
        }
    }
}

// ---------------------------------------------------------------------------
// Sort stage 1: 18 chunk-sorts of 2048 per batch (36864 = 18*2048).
// ---------------------------------------------------------------------------
__device__ inline void cmp_stage(U64* s, int j, int k, int tid) {
    for (int p = tid; p < 1024; p += 256) {
        int il = ((p & ~(j - 1)) << 1) | (p & (j - 1));
        int ip = il | j;
        U64 a = s[il], c = s[ip];
        bool desc = ((il & k) == 0);
        bool sw = desc ? (a < c) : (a > c);
        if (sw) { s[il] = c; s[ip] = a; }
    }
}

__global__ __launch_bounds__(256) void k_sort_chunk(const U64* __restrict__ keys,
                                                    U64* __restrict__ run) {
    __shared__ U64 s[2048];
    int b = blockIdx.x / 18, ch = blockIdx.x % 18;
    int tid = threadIdx.x;
    const U64* src = keys + (size_t)b * 36864 + ch * 2048;
    for (int e = tid; e < 2048; e += 256) s[e] = src[e];
    __syncthreads();
    for (int k = 2; k <= 2048; k <<= 1)
        for (int j = k >> 1; j >= 1; j >>= 1) {
            cmp_stage(s, j, k, tid);
            __syncthreads();
        }
    U64* dst = run + ((size_t)b * 18 + ch) * 2048;
    for (int e = tid; e < 2048; e += 256) dst[e] = s[e];
}

// ---------------------------------------------------------------------------
// K_merge_all: one block per batch; champion top-2048 in LDS, stream the other
// 17 runs through {reversed-load, half-clean, 11-stage desc merge}. Then the
// top-2000 gather + clip + min-size filter, fused.
// ---------------------------------------------------------------------------
__global__ __launch_bounds__(256) void k_merge_all(const U64* __restrict__ run,
                                                   const float4* __restrict__ proposals,
                                                   float4* __restrict__ tb_boxes,
                                                   float* __restrict__ tb_scores) {
    __shared__ U64 s[4096];
    int b = blockIdx.x, tid = threadIdx.x;
    const U64* base = run + (size_t)b * 18 * 2048;
    for (int e = tid; e < 2048; e += 256) s[e] = base[e];
    for (int m = 1; m < 18; ++m) {
        for (int e = tid; e < 2048; e += 256) s[4095 - e] = base[(size_t)m * 2048 + e];
        __syncthreads();
        for (int e = tid; e < 2048; e += 256) {
            U64 a = s[e], c = s[e + 2048];
            s[e] = (a >= c) ? a : c;
        }
        __syncthreads();
        for (int j = 1024; j >= 1; j >>= 1) {
            for (int p = tid; p < 1024; p += 256) {
                int il = ((p & ~(j - 1)) << 1) | (p & (j - 1));
                int ip = il | j;
                U64 a = s[il], c = s[ip];
                if (a < c) { s[il] = c; s[ip] = a; }
            }
            __syncthreads();
        }
    }
    for (int r = tid; r < 2000; r += 256) {
        U64 key = s[r];
        unsigned n = ~((unsigned)key);
        float sc = __uint_as_float(((unsigned)(key >> 32)) ^ 0x80000000u);
        float4 p = proposals[b * 36864 + (int)n];
        float x1 = fminf(fmaxf(p.x, 0.f), 1024.f);
        float y1 = fminf(fmaxf(p.y, 0.f), 1024.f);
        float x2 = fminf(fmaxf(p.z, 0.f), 1024.f);
        float y2 = fminf(fmaxf(p.w, 0.f), 1024.f);
        bool small_ = ((x2 - x1) < 16.f) || ((y2 - y1) < 16.f);
        tb_boxes[b * 2000 + r] = make_float4(x1, y1, x2, y2);
        tb_scores[b * 2000 + r] = small_ ? -INFINITY : sc;
    }
}

// ---------------------------------------------------------------------------
// K_nms_mask: suppression bitmask. mask[b][i][jt] bit jj = (j>i && iou>0.7).
// ---------------------------------------------------------------------------
__global__ __launch_bounds__(64) void k_nms_mask(const float4* __restrict__ tb_boxes,
                                                 U64* __restrict__ mask) {
    int jt = blockIdx.x, it = blockIdx.y, b = blockIdx.z;
    int tid = threadIdx.x;
    __shared__ float4 jb[64];
    int j0 = jt * 64;
    {
        int j = j0 + tid;
        jb[tid] = (j < 2000) ? tb_boxes[b * 2000 + j] : make_float4(0.f, 0.f, 0.f, 0.f);
    }
    __syncthreads();
    int i = it * 64 + tid;
    if (i >= 2000) return;
    float4 bi = tb_boxes[b * 2000 + i];
    float ai = (bi.z - bi.x) * (bi.w - bi.y);
    U64 bits = 0;
#pragma unroll 4
    for (int jj = 0; jj < 64; ++jj) {
        int j = j0 + jj;
        float4 bj = jb[jj];
        float aj = (bj.z - bj.x) * (bj.w - bj.y);
        float ltx = fmaxf(bi.x, bj.x), lty = fmaxf(bi.y, bj.y);
        float rbx = fminf(bi.z, bj.z), rby = fminf(bi.w, bj.w);
        float ww = fmaxf(rbx - ltx, 0.f), hh2 = fmaxf(rby - lty, 0.f);
        float inter = ww * hh2;
        float iou = inter / (ai + aj - inter);
        if ((j > i) && (j < 2000) && (iou > 0.7f)) bits |= (1ull << jj);
    }
    mask[((size_t)b * 2000 + i) * 32 + jt] = bits;
}

// ---------------------------------------------------------------------------
// K_nms_scan: sequential NMS scan (1 wave/batch), mask chunks in registers.
// ---------------------------------------------------------------------------
__global__ __launch_bounds__(64) void k_nms_scan(const float4* __restrict__ tb_boxes,
                                                 const float* __restrict__ tb_scores,
                                                 const U64* __restrict__ mask,
                                                 float* __restrict__ out) {
    int b = blockIdx.x;
    int lane = threadIdx.x;
    __shared__ unsigned short keeplist[2000];
    __shared__ unsigned char keepflag[2000];
    __shared__ unsigned short fillq[304];

    U64 remv = 0;
    if (lane < 32) {
        for (int jj = 0; jj < 64; ++jj) {
            int j = (lane << 6) | jj;
            if (j < 2000 && tb_scores[b * 2000 + j] == -INFINITY) remv |= (1ull << jj);
        }
    }
    const U64* mb = mask + (size_t)b * 2000 * 32;

    U64 cva[32], cvb[32];
    int nkeep = 0;

    auto loadchunk = [&](U64 (&cv)[32], int ch) {
#pragma unroll
        for (int q = 0; q < 32; ++q) {
            int row = ch * 64 + q * 2 + (lane >> 5), wd = lane & 31;
            cv[q] = (row < 2000) ? mb[(size_t)row * 32 + wd] : 0ull;
        }
    };
    auto process = [&](U64 (&cv)[32], int ch) {
        int base = ch * 64;
        int iend = (2000 - base < 64) ? (2000 - base) : 64;
        U64 w_all = __shfl(remv, ch);
#pragma unroll
        for (int ii = 0; ii < 64; ++ii) {
            if (ii < iend) {
                bool sup = (w_all >> ii) & 1ull;
                int i = base + ii;
                if (!sup) {
                    if (lane == 0) keeplist[nkeep] = (unsigned short)i;
                    U64 mrow = __shfl(cv[ii >> 1], ((ii & 1) << 5) | (lane & 31));
                    if (lane < 32) remv |= mrow;
                    w_all |= __shfl(cv[ii >> 1], ((ii & 1) << 5) | ch);
                    nkeep++;
                }
                if (lane == 0) keepflag[i] = sup ? (unsigned char)0 : (unsigned char)1;
            }
        }
    };

    loadchunk(cva, 0);
    for (int ch2 = 0; ch2 < 32; ch2 += 2) {
        loadchunk(cvb, ch2 + 1);
        process(cva, ch2);
        if (ch2 + 2 < 32) loadchunk(cva, ch2 + 2);
        process(cvb, ch2 + 1);
    }
    __syncthreads();

    if (lane == 0) {
        int need = 300 - nkeep, c = 0;
        for (int i = 0; i < 2000 && c < need; ++i)
            if (!keepflag[i]) fillq[c++] = (unsigned short)i;
    }
    __syncthreads();
    for (int r = lane; r < 300; r += 64) {
        int src; float sc;
        if (r < nkeep) { src = keeplist[r]; sc = tb_scores[b * 2000 + src]; }
        else           { src = fillq[r - nkeep]; sc = -INFINITY; }
        float4 bx = tb_boxes[b * 2000 + src];
        int ob = (b * 300 + r) * 4;
        out[ob + 0] = bx.x; out[ob + 1] = bx.y; out[ob + 2] = bx.z; out[ob + 3] = bx.w;
        out[4800 + b * 300 + r] = sc;
    }
}

// ---------------------------------------------------------------------------
extern "C" void kernel_launch(void* const* d_in, const int* in_sizes, int n_in,
                              void* d_out, int out_size, void* d_ws, size_t ws_size,
                              hipStream_t stream) {
    (void)in_sizes; (void)n_in; (void)out_size; (void)ws_size;
    const float* feature_map = (const float*)d_in[1];
    const float* w_conv = (const float*)d_in[2];
    const float* b_conv = (const float*)d_in[3];
    const float* w_cls  = (const float*)d_in[4];
    const float* b_cls  = (const float*)d_in[5];
    const float* w_box  = (const float*)d_in[6];
    const float* b_box  = (const float*)d_in[7];
    float* out = (float*)d_out;

    char* ws = (char*)d_ws;
    size_t off = 0;
    auto alloc = [&](size_t bytes) {
        void* p = ws + off;
        off = (off + bytes + 255) & ~(size_t)255;
        return p;
    };
    const size_t fpi_elems = 4ull * 66 * 66 * 1024;            // 17.8M f16
    _Float16* fpi = (_Float16*)alloc(fpi_elems * 2);           // 35.7 MB
    _Float16* wki = (_Float16*)alloc(512ull * 9216 * 2);       // 9.4 MB
    float*  feat      = (float*) alloc(16384ull * 512 * 4);    // 33.6 MB
    float4* proposals = (float4*)alloc(4ull * 36864 * 16);     // 2.4 MB
    U64*    keys      = (U64*)   alloc(4ull * 36864 * 8);      // 1.2 MB
    U64*    run0      = (U64*)   alloc(4ull * 18 * 2048 * 8);  // 1.2 MB
    float4* tb_boxes  = (float4*)alloc(8000ull * 16);
    float*  tb_scores = (float*) alloc(8000ull * 4);
    U64*    nmsmask   = (U64*)   alloc(8000ull * 32 * 8);      // 2.0 MB

    k_prep<<<dim3(900, 4), 256, 0, stream>>>(feature_map, w_conv, fpi, wki);
    k_conv_mfma<<<dim3(128, 4), 256, 0, stream>>>(fpi, wki, b_conv, feat);
    k_heads<<<256, 256, 0, stream>>>(feat, w_cls, b_cls, w_box, b_box, keys, proposals);
    k_sort_chunk<<<72, 256, 0, stream>>>(keys, run0);
    k_merge_all<<<4, 256, 0, stream>>>(run0, proposals, tb_boxes, tb_scores);
    k_nms_mask<<<dim3(32, 32, 4), 64, 0, stream>>>(tb_boxes, nmsmask);
    k_nms_scan<<<4, 64, 0, stream>>>(tb_boxes, tb_scores, nmsmask, out);
}